// Round 16
// baseline (234.014 us; speedup 1.0000x reference)
//
#include <hip/hip_runtime.h>
#include <hip/hip_bf16.h>

// DecoderLSTM: B=256, S=512, H=512, E=256, V=16000
#define B_ 256
#define S_ 512
#define H_ 512
#define E_ 256
#define V_ 16000

typedef __attribute__((ext_vector_type(4))) float f32x4_t;
typedef __attribute__((ext_vector_type(2))) float f32x2_t;
typedef __attribute__((ext_vector_type(8))) short bf16x8_t;
typedef __attribute__((ext_vector_type(2))) unsigned u32x2_t;
typedef __attribute__((ext_vector_type(4))) unsigned u32x4_t;

#define W2_SCALE 64.0f
#define W2_INV   0.015625f

// packed f32->bf16 RNE, 1 inst per 2 elems
__device__ __forceinline__ bf16x8_t pack8(f32x4_t a, f32x4_t b) {
    union { unsigned u[4]; bf16x8_t v; } o;
    asm("v_cvt_pk_bf16_f32 %0, %1, %2" : "=v"(o.u[0]) : "v"(a[0]), "v"(a[1]));
    asm("v_cvt_pk_bf16_f32 %0, %1, %2" : "=v"(o.u[1]) : "v"(a[2]), "v"(a[3]));
    asm("v_cvt_pk_bf16_f32 %0, %1, %2" : "=v"(o.u[2]) : "v"(b[0]), "v"(b[1]));
    asm("v_cvt_pk_bf16_f32 %0, %1, %2" : "=v"(o.u[3]) : "v"(b[2]), "v"(b[3]));
    return o.v;
}

__device__ __forceinline__ void cvt8(short* dst, const float* src) {
    f32x4_t a = *(const f32x4_t*)src;
    f32x4_t b = *(const f32x4_t*)(src + 4);
    *(bf16x8_t*)dst = pack8(a, b);
}

// 8 f32 -> 8 fp8 e4m3 packed in 2 dwords (4 cvt_pk inst)
__device__ __forceinline__ u32x2_t f32x8_to_fp8x8(f32x4_t a, f32x4_t b, float s) {
    unsigned d0 = 0, d1 = 0;
    d0 = __builtin_amdgcn_cvt_pk_fp8_f32(a[0] * s, a[1] * s, d0, false);
    d0 = __builtin_amdgcn_cvt_pk_fp8_f32(a[2] * s, a[3] * s, d0, true);
    d1 = __builtin_amdgcn_cvt_pk_fp8_f32(b[0] * s, b[1] * s, d1, false);
    d1 = __builtin_amdgcn_cvt_pk_fp8_f32(b[2] * s, b[3] * s, d1, true);
    u32x2_t r; r[0] = d0; r[1] = d1;
    return r;
}

// tanh = 1 - 2/(exp(2x)+1): 5 flat VALU, saturates correctly at +-inf
__device__ __forceinline__ float tanh5(float x) {
    float e = __expf(2.f * x);
    return 1.f - 2.f * __builtin_amdgcn_rcpf(e + 1.f);
}

// LDS chunk swizzle: row has 64 chunks; interleave chunk bits + XOR row.
__device__ __forceinline__ int physc(int c, int r) {
    return ((((c & 7) << 3) | (c >> 3)) ^ (r & 7));
}

// ---------------------------------------------------------------------------
// pack_w2: attn_W second half (W2), scaled x64 -> PAIRED fp8, 16-wave layout.
// 16B unit u = (kk*16 + w)*64 + lane:
//   bytes 0-7  = W2[col = w*32   +(lane&15)][k..k+8) * 64
//   bytes 8-15 = W2[col = w*32+16+(lane&15)][k..k+8) * 64
// with k = kk*32+(lane>>4)*8. One dwordx4 per lane covers both nf fragments.
// ---------------------------------------------------------------------------
__global__ void pack_w2(const float* __restrict__ attn_W, unsigned* __restrict__ Bp)
{
    const int u    = blockIdx.x * 256 + threadIdx.x;       // 16384 units
    const int lane = u & 63;
    const int w    = (u >> 6) & 15;
    const int kk   = u >> 10;                              // 0..15
    const int col0 = w * 32 + (lane & 15);
    const int k    = kk * 32 + (lane >> 4) * 8;
    const float* s0 = attn_W + (size_t)col0 * (2 * H_) + H_ + k;
    const float* s1 = s0 + (size_t)16 * (2 * H_);          // col0 + 16
    f32x4_t a0 = *(const f32x4_t*)s0, b0 = *(const f32x4_t*)(s0 + 4);
    f32x4_t a1 = *(const f32x4_t*)s1, b1 = *(const f32x4_t*)(s1 + 4);
    u32x2_t lo = f32x8_to_fp8x8(a0, b0, W2_SCALE);
    u32x2_t hi = f32x8_to_fp8x8(a1, b1, W2_SCALE);
    u32x4_t st; st[0] = lo[0]; st[1] = lo[1]; st[2] = hi[0]; st[3] = hi[1];
    *(u32x4_t*)(Bp + (size_t)u * 4) = st;
}

// ---------------------------------------------------------------------------
// bias1: h @ W1^T + attn_b.  128 blocks x 512 thr, 2 batches per block.
// ---------------------------------------------------------------------------
__global__ void bias1_kernel(const float* __restrict__ hidden,
                             const float* __restrict__ attn_W,
                             const float* __restrict__ attn_b,
                             float* __restrict__ bias1)
{
    const int t  = threadIdx.x;                // output col
    const int b0 = blockIdx.x * 2;
    __shared__ float h_s[2][512];
    h_s[0][t] = hidden[(size_t)b0 * H_ + t];
    h_s[1][t] = hidden[(size_t)(b0 + 1) * H_ + t];
    __syncthreads();
    const float* wrow = attn_W + (size_t)t * (2 * H_);     // W1 part: cols 0..511
    float a0 = 0.f, a1 = 0.f;
#pragma unroll 4
    for (int k = 0; k < 512; k += 4) {
        f32x4_t wv = *(const f32x4_t*)(wrow + k);
        a0 = fmaf(wv[0], h_s[0][k],     a0);
        a0 = fmaf(wv[1], h_s[0][k + 1], a0);
        a0 = fmaf(wv[2], h_s[0][k + 2], a0);
        a0 = fmaf(wv[3], h_s[0][k + 3], a0);
        a1 = fmaf(wv[0], h_s[1][k],     a1);
        a1 = fmaf(wv[1], h_s[1][k + 1], a1);
        a1 = fmaf(wv[2], h_s[1][k + 2], a1);
        a1 = fmaf(wv[3], h_s[1][k + 3], a1);
    }
    const float bb = attn_b[t];
    bias1[(size_t)b0 * H_ + t]       = a0 + bb;
    bias1[(size_t)(b0 + 1) * H_ + t] = a1 + bb;
}

// ---------------------------------------------------------------------------
// fused_attn: 2048 blocks (8 per batch, ONE 64-row tile each), 1024 threads
// (16 waves). Halves B L2 re-read (0.5 GB total, was 1 GB) and B VMEM issues
// (16 dwordx4/thread/tile, was 32) vs r15's 32-row blocks. Wave owns 64x32 ->
// acc[4][2] = 32 VGPR: the r8/r14-proven shape that FITS the hard 64-VGPR
// budget of >=4-waves/EU configs (this loop is strictly smaller - native fp8
// MFMA, no conversion temps). LDS ~41 KB -> 2 blocks/CU = 32 waves = full
// occupancy. Outputs partial e / l / ctx per 64-row slice; combine merges 8.
// ---------------------------------------------------------------------------
__global__ void fused_attn(const float* __restrict__ enc,
                           const unsigned* __restrict__ Bp,
                           const float* __restrict__ bias1,
                           const float* __restrict__ vvec,
                           float* __restrict__ e_ws,
                           float* __restrict__ lpart,
                           float* __restrict__ ctxpart)
{
    __shared__ unsigned char buf8[64 * 512]; // 32 KB fp8 tile, swizzled 8B chunks
    __shared__ float bias_s[512];
    __shared__ float v_s[512];
    __shared__ float red[64][17];
    __shared__ float e_loc[64];

    const int t    = threadIdx.x;            // 0..1023
    const int lane = t & 63;
    const int w    = t >> 6;                 // 0..15, col group (32 cols)
    const int b    = blockIdx.x >> 3;        // batch
    const int q    = blockIdx.x & 7;         // 64-row slice

    if (t < 512) {
        bias_s[t] = bias1[(size_t)b * H_ + t];
        v_s[t]    = vvec[t];
    }

    // ---- stage 64x512 f32 -> fp8 swizzled LDS (128B coalesced/thread)
    const int srow = t >> 4;                 // 0..63
    const int sc   = t & 15;
    const float* gp = enc + ((size_t)b * S_ + q * 64 + srow) * H_ + sc * 32;
#pragma unroll
    for (int i = 0; i < 4; ++i) {
        f32x4_t a = *(const f32x4_t*)(gp + i * 8);
        f32x4_t c = *(const f32x4_t*)(gp + i * 8 + 4);
        *(u32x2_t*)&buf8[srow * 512 + physc(sc * 4 + i, srow) * 8] =
            f32x8_to_fp8x8(a, c, 1.0f);
    }
    __syncthreads();

    // ---- GEMM: 64 rows x 32 cols (this wave) x K=512, fp8 x fp8
    const int l15 = lane & 15;
    const int hi  = lane >> 4;               // 0..3
    const int Y   = l15 & 7;
    const unsigned char* abase = buf8 + l15 * 512 + hi * 64; // + mf*8192, par*256 imm
    const unsigned* bbase = Bp + (size_t)w * 256 + lane * 4; // + kk2*8192 + par*4096

    f32x4_t acc[4][2];
#pragma unroll
    for (int mf = 0; mf < 4; ++mf) {
        acc[mf][0] = (f32x4_t){0.f, 0.f, 0.f, 0.f};
        acc[mf][1] = (f32x4_t){0.f, 0.f, 0.f, 0.f};
    }

#pragma unroll
    for (int kk2 = 0; kk2 < 8; ++kk2) {
        const unsigned char* ap = abase + ((kk2 ^ Y) << 3);
        const unsigned* bp = bbase + (size_t)kk2 * 8192;
#pragma unroll
        for (int par = 0; par < 2; ++par) {
            const unsigned char* app = ap + par * 256;
            union { u32x4_t v; long l[2]; } q0;
            q0.v = *(const u32x4_t*)(bp + par * 4096);  // frags nf0, nf1
            long a0 = *(const long*)(app);
            long a1 = *(const long*)(app + 8192);
            long a2 = *(const long*)(app + 16384);
            long a3 = *(const long*)(app + 24576);
            __builtin_amdgcn_s_setprio(1);
            acc[0][0] = __builtin_amdgcn_mfma_f32_16x16x32_fp8_fp8(a0, q0.l[0], acc[0][0], 0, 0, 0);
            acc[1][0] = __builtin_amdgcn_mfma_f32_16x16x32_fp8_fp8(a1, q0.l[0], acc[1][0], 0, 0, 0);
            acc[2][0] = __builtin_amdgcn_mfma_f32_16x16x32_fp8_fp8(a2, q0.l[0], acc[2][0], 0, 0, 0);
            acc[3][0] = __builtin_amdgcn_mfma_f32_16x16x32_fp8_fp8(a3, q0.l[0], acc[3][0], 0, 0, 0);
            acc[0][1] = __builtin_amdgcn_mfma_f32_16x16x32_fp8_fp8(a0, q0.l[1], acc[0][1], 0, 0, 0);
            acc[1][1] = __builtin_amdgcn_mfma_f32_16x16x32_fp8_fp8(a1, q0.l[1], acc[1][1], 0, 0, 0);
            acc[2][1] = __builtin_amdgcn_mfma_f32_16x16x32_fp8_fp8(a2, q0.l[1], acc[2][1], 0, 0, 0);
            acc[3][1] = __builtin_amdgcn_mfma_f32_16x16x32_fp8_fp8(a3, q0.l[1], acc[3][1], 0, 0, 0);
            __builtin_amdgcn_s_setprio(0);
        }
    }

    // ---- epilogue: per-wave partial score over its 32 cols
    float part[16];
#pragma unroll
    for (int i = 0; i < 16; ++i) part[i] = 0.f;
#pragma unroll
    for (int nf = 0; nf < 2; ++nf) {
        const int col = w * 32 + nf * 16 + l15;
        const float bbv = bias_s[col];
        const float vl  = v_s[col];
#pragma unroll
        for (int mf = 0; mf < 4; ++mf)
#pragma unroll
            for (int r = 0; r < 4; ++r)
                part[mf * 4 + r] += vl * tanh5(fmaf(acc[mf][nf][r], W2_INV, bbv));
    }
#pragma unroll
    for (int i = 0; i < 16; ++i) {
        float p = part[i];
        p += __shfl_xor(p, 1);
        p += __shfl_xor(p, 2);
        p += __shfl_xor(p, 4);
        p += __shfl_xor(p, 8);
        part[i] = p;
    }
    if (l15 == 0) {
#pragma unroll
        for (int mf = 0; mf < 4; ++mf)
#pragma unroll
            for (int r = 0; r < 4; ++r)
                red[mf * 16 + (hi << 2) + r][w] = part[mf * 4 + r];
    }
    __syncthreads();                          // red visible

    if (t < 64) {
        float s = 0.f;
#pragma unroll
        for (int g = 0; g < 16; ++g) s += red[t][g];
        e_loc[t] = __expf(s);
    }
    __syncthreads();                          // e_loc visible

    // ---- context partial from fp8 tile: rows r = i*16+rg, chunk cc
    const int cc = t >> 4;                    // 0..63
    const int rg = t & 15;
    float acc8[8];
#pragma unroll
    for (int j = 0; j < 8; ++j) acc8[j] = 0.f;
#pragma unroll
    for (int i = 0; i < 4; ++i) {
        const int r   = i * 16 + rg;
        const float e = e_loc[r];
        u32x2_t ch = *(const u32x2_t*)&buf8[r * 512 + physc(cc, r) * 8];
        f32x2_t f0 = __builtin_amdgcn_cvt_pk_f32_fp8(ch[0], false);
        f32x2_t f1 = __builtin_amdgcn_cvt_pk_f32_fp8(ch[0], true);
        f32x2_t f2 = __builtin_amdgcn_cvt_pk_f32_fp8(ch[1], false);
        f32x2_t f3 = __builtin_amdgcn_cvt_pk_f32_fp8(ch[1], true);
        acc8[0] = fmaf(e, f0[0], acc8[0]);
        acc8[1] = fmaf(e, f0[1], acc8[1]);
        acc8[2] = fmaf(e, f1[0], acc8[2]);
        acc8[3] = fmaf(e, f1[1], acc8[3]);
        acc8[4] = fmaf(e, f2[0], acc8[4]);
        acc8[5] = fmaf(e, f2[1], acc8[5]);
        acc8[6] = fmaf(e, f3[0], acc8[6]);
        acc8[7] = fmaf(e, f3[1], acc8[7]);
    }
    // reduce over the 16 consecutive lanes sharing chunk cc
#pragma unroll
    for (int m = 1; m < 16; m <<= 1)
#pragma unroll
        for (int j = 0; j < 8; ++j)
            acc8[j] += __shfl_xor(acc8[j], m);
#pragma unroll
    for (int j = 0; j < 8; ++j)               // static index (rule #20)
        if (rg == j)
            ctxpart[(size_t)blockIdx.x * H_ + cc * 8 + j] = acc8[j];

    // ---- l partial + e out (64 rows; t<64 = wave 0, full 64-lane reduce)
    if (t < 64) {
        float sv = e_loc[t];
        sv += __shfl_xor(sv, 1);
        sv += __shfl_xor(sv, 2);
        sv += __shfl_xor(sv, 4);
        sv += __shfl_xor(sv, 8);
        sv += __shfl_xor(sv, 16);
        sv += __shfl_xor(sv, 32);
        if (lane == 0) lpart[blockIdx.x] = sv;
        e_ws[(size_t)b * S_ + q * 64 + t] = e_loc[t];
    }
}

// ---------------------------------------------------------------------------
// combine: normalize softmax pieces from the 8 row-slice blocks per batch.
// ---------------------------------------------------------------------------
__global__ void combine_kernel(const float* __restrict__ e_ws,
                               const float* __restrict__ lpart,
                               const float* __restrict__ ctxpart,
                               float* __restrict__ out_attn,
                               short* __restrict__ x_cat)
{
    const int b = blockIdx.x, t = threadIdx.x;          // 512 threads
    float l = 0.f;
#pragma unroll
    for (int j = 0; j < 8; ++j) l += lpart[8 * b + j];
    const float li = 1.f / l;
    out_attn[(size_t)b * S_ + t] = e_ws[(size_t)b * S_ + t] * li;
    float ctx = 0.f;
#pragma unroll
    for (int j = 0; j < 8; ++j)
        ctx += ctxpart[(size_t)(8 * b + j) * H_ + t];
    union { float f; unsigned u; } v; v.f = ctx * li;
    unsigned r = v.u + 0x7fffu + ((v.u >> 16) & 1u);
    x_cat[(size_t)b * 1280 + 256 + t] = (short)(r >> 16);
}

// ---------------------------------------------------------------------------
// gemm_std: BM=128, BN=128, BK=32, 4 waves (256 thr). A is pre-converted bf16.
// KIND 0 (gates): split-K via blockIdx.z (2 halves of 640), NO bias (lstm
//                 adds b_ih+b_hh when summing the two partials).
// KIND 1 (pred):  K=512, N=16000, B = fc_W rows, bias = fc_b.
// ---------------------------------------------------------------------------
template<int KIND>
__global__ __launch_bounds__(256, 2)
void gemm_std(const short* __restrict__ Abf,
              const float* __restrict__ B0,
              const float* __restrict__ B1,
              const float* __restrict__ bias0,
              float* __restrict__ out)
{
    constexpr int K = (KIND == 0) ? 1280 : 512;
    constexpr int N = (KIND == 0) ? 2048 : 16000;
    constexpr int KITER = (KIND == 0) ? 20 : 16;         // ks steps per block

    __shared__ short As[128 * 40];
    __shared__ short Bs[128 * 40];

    const int t    = threadIdx.x;
    const int lane = t & 63;
    const int w    = t >> 6;
    const int wm   = w >> 1;
    const int wn   = w & 1;
    const int row0 = blockIdx.x * 128;
    const int col0 = blockIdx.y * 128;
    const int z    = (KIND == 0) ? blockIdx.z : 0;
    const int ks0  = z * KITER;
    float* outp    = (KIND == 0) ? out + (size_t)z * 256 * 2048 : out;

    f32x4_t acc[4][4];
#pragma unroll
    for (int i = 0; i < 4; ++i)
#pragma unroll
        for (int j = 0; j < 4; ++j)
            acc[i][j] = (f32x4_t){0.f, 0.f, 0.f, 0.f};

    const int arow = t >> 1, ah = (t & 1) * 16;
    const int bcol = t >> 1, bh = (t & 1) * 16;

    for (int ksi = 0; ksi < KITER; ++ksi) {
        const int k0 = (ks0 + ksi) * 32;
        __syncthreads();
        const short* asrc = Abf + (size_t)(row0 + arow) * K + k0 + ah;
        *(bf16x8_t*)&As[arow * 40 + ah]     = *(const bf16x8_t*)asrc;
        *(bf16x8_t*)&As[arow * 40 + ah + 8] = *(const bf16x8_t*)(asrc + 8);
        const float* bsrc;
        if constexpr (KIND == 0) {
            const int cg = col0 + bcol;
            bsrc = (k0 < 768) ? (B0 + (size_t)cg * 768 + k0 + bh)
                              : (B1 + (size_t)cg * 512 + (k0 - 768) + bh);
        } else {
            bsrc = B0 + (size_t)(col0 + bcol) * 512 + k0 + bh;
        }
        cvt8(&Bs[bcol * 40 + bh],     bsrc);
        cvt8(&Bs[bcol * 40 + bh + 8], bsrc + 8);
        __syncthreads();

        bf16x8_t af[4], bfr[4];
        const int ka = (lane >> 4) * 8;
#pragma unroll
        for (int mf = 0; mf < 4; ++mf)
            af[mf] = *(const bf16x8_t*)&As[(wm * 64 + mf * 16 + (lane & 15)) * 40 + ka];
#pragma unroll
        for (int nf = 0; nf < 4; ++nf)
            bfr[nf] = *(const bf16x8_t*)&Bs[(wn * 64 + nf * 16 + (lane & 15)) * 40 + ka];
#pragma unroll
        for (int mf = 0; mf < 4; ++mf)
#pragma unroll
            for (int nf = 0; nf < 4; ++nf)
                acc[mf][nf] = __builtin_amdgcn_mfma_f32_16x16x32_bf16(
                    af[mf], bfr[nf], acc[mf][nf], 0, 0, 0);
    }

#pragma unroll
    for (int mf = 0; mf < 4; ++mf)
#pragma unroll
        for (int nf = 0; nf < 4; ++nf) {
            const int col  = col0 + wn * 64 + nf * 16 + (lane & 15);
            const int rowb = row0 + wm * 64 + mf * 16 + ((lane >> 4) << 2);
#pragma unroll
            for (int r = 0; r < 4; ++r) {
                float v = acc[mf][nf][r];
                if constexpr (KIND == 1) v += bias0[col];
                outp[(size_t)(rowb + r) * N + col] = v;
            }
        }
}

// ---------------------------------------------------------------------------
// small kernels
// ---------------------------------------------------------------------------
__global__ void prep_kernel(const int* __restrict__ tgt,
                            const float* __restrict__ emb,
                            const float* __restrict__ hidden,
                            short* __restrict__ x_cat)
{
    const int b = blockIdx.x, t = threadIdx.x;          // 256 threads
    const int tok = tgt[b];
    union { float f; unsigned u; } v0, v1, v2;
    v0.f = emb[(size_t)tok * E_ + t];
    v1.f = hidden[(size_t)b * H_ + t];
    v2.f = hidden[(size_t)b * H_ + 256 + t];
    unsigned r0 = v0.u + 0x7fffu + ((v0.u >> 16) & 1u);
    unsigned r1 = v1.u + 0x7fffu + ((v1.u >> 16) & 1u);
    unsigned r2 = v2.u + 0x7fffu + ((v2.u >> 16) & 1u);
    x_cat[(size_t)b * 1280 + t]             = (short)(r0 >> 16);
    x_cat[(size_t)b * 1280 + 768 + t]       = (short)(r1 >> 16);
    x_cat[(size_t)b * 1280 + 768 + 256 + t] = (short)(r2 >> 16);
}

// lstm: sums the two split-K gate partials + both biases, then pointwise.
__global__ void lstm_kernel(const float* __restrict__ gates0,
                            const float* __restrict__ gates1,
                            const float* __restrict__ b_ih,
                            const float* __restrict__ b_hh,
                            const float* __restrict__ cell,
                            float* __restrict__ out_h,
                            float* __restrict__ out_c,
                            short* __restrict__ h_bf)
{
    const int b = blockIdx.x, t = threadIdx.x;          // 512 threads
    const float* g0 = gates0 + (size_t)b * 2048;
    const float* g1 = gates1 + (size_t)b * 2048;
    const float gi = g0[t]        + g1[t]        + b_ih[t]        + b_hh[t];
    const float gf = g0[512 + t]  + g1[512 + t]  + b_ih[512 + t]  + b_hh[512 + t];
    const float gg = g0[1024 + t] + g1[1024 + t] + b_ih[1024 + t] + b_hh[1024 + t];
    const float go = g0[1536 + t] + g1[1536 + t] + b_ih[1536 + t] + b_hh[1536 + t];
    const float c  = cell[(size_t)b * H_ + t];
    const float si = 1.f / (1.f + __expf(-gi));
    const float sf = 1.f / (1.f + __expf(-gf));
    const float so = 1.f / (1.f + __expf(-go));
    const float cn = sf * c + si * tanhf(gg);
    const float hn = so * tanhf(cn);
    out_h[(size_t)b * H_ + t] = hn;
    out_c[(size_t)b * H_ + t] = cn;
    union { float f; unsigned u; } v; v.f = hn;
    unsigned r = v.u + 0x7fffu + ((v.u >> 16) & 1u);
    h_bf[(size_t)b * H_ + t]  = (short)(r >> 16);
}

// ---------------------------------------------------------------------------
extern "C" void kernel_launch(void* const* d_in, const int* in_sizes, int n_in,
                              void* d_out, int out_size, void* d_ws, size_t ws_size,
                              hipStream_t stream)
{
    (void)in_sizes; (void)n_in; (void)out_size; (void)ws_size;

    const int*   tgt    = (const int*)d_in[0];
    const float* hidden = (const float*)d_in[1];
    const float* cell   = (const float*)d_in[2];
    const float* enc    = (const float*)d_in[3];
    const float* emb    = (const float*)d_in[4];
    const float* attn_W = (const float*)d_in[5];
    const float* attn_b = (const float*)d_in[6];
    const float* vv     = (const float*)d_in[7];
    const float* W_ih   = (const float*)d_in[8];
    const float* W_hh   = (const float*)d_in[9];
    const float* b_ih   = (const float*)d_in[10];
    const float* b_hh   = (const float*)d_in[11];
    const float* fc_W   = (const float*)d_in[12];
    const float* fc_b   = (const float*)d_in[13];

    float* out_pred = (float*)d_out;                       // [256][16000]
    float* out_h    = out_pred + (size_t)B_ * V_;          // [256][512]
    float* out_c    = out_h + (size_t)B_ * H_;             // [256][512]
    float* out_attn = out_c + (size_t)B_ * H_;             // [256][512]

    char*  ws      = (char*)d_ws;
    float* bias1   = (float*)ws;                           // 131072 f32
    float* gates01 = bias1 + (size_t)B_ * H_;              // 2 x 524288 f32
    float* e_ws    = gates01 + (size_t)2 * B_ * 2048;      // 131072 f32
    float* lpart   = e_ws + (size_t)B_ * S_;               // 2048 f32
    float* ctxpart = lpart + 2048;                         // 2048*512 f32
    short* x_cat   = (short*)(ctxpart + (size_t)2048 * H_);// 327680 bf16
    short* h_bf    = x_cat + (size_t)B_ * 1280;            // 131072 bf16
    unsigned* b2p  = (unsigned*)(h_bf + (size_t)B_ * H_);  // 65536 dwords (fp8)

    // 0. pack W2 half into paired fragment-ordered fp8 (x64), 16-wave layout
    pack_w2<<<64, 256, 0, stream>>>(attn_W, b2p);
    // 1. embedding gather + h into x_cat (bf16)
    prep_kernel<<<B_, 256, 0, stream>>>(tgt, emb, hidden, x_cat);
    // 2. bias1 = h @ W1^T + attn_b
    bias1_kernel<<<128, 512, 0, stream>>>(hidden, attn_W, attn_b, bias1);
    // 3. fused attention partials: 8 blocks per batch (64 rows each)
    fused_attn<<<8 * B_, 1024, 0, stream>>>(enc, b2p, bias1, vv, e_ws, lpart, ctxpart);
    // 4. combine partials -> attn out + ctx slice of x_cat
    combine_kernel<<<B_, 512, 0, stream>>>(e_ws, lpart, ctxpart, out_attn, x_cat);
    // 5. gates partials = x_cat @ [W_ih|W_hh]^T  (split-K, 2 halves, no bias)
    gemm_std<0><<<dim3(2, 16, 2), 256, 0, stream>>>(x_cat, W_ih, W_hh, nullptr, gates01);
    // 6. LSTM pointwise (sums partials + biases)
    lstm_kernel<<<B_, 512, 0, stream>>>(gates01, gates01 + (size_t)B_ * 2048,
                                        b_ih, b_hh, cell, out_h, out_c, h_bf);
    // 7. prediction = h_new @ fc_W^T + fc_b
    gemm_std<1><<<dim3(2, 125), 256, 0, stream>>>(h_bf, fc_W, nullptr, fc_b, out_pred);
}

// Round 17
// 192.621 us; speedup vs baseline: 1.2149x; 1.2149x over previous
//
#include <hip/hip_runtime.h>
#include <hip/hip_bf16.h>

// DecoderLSTM: B=256, S=512, H=512, E=256, V=16000
#define B_ 256
#define S_ 512
#define H_ 512
#define E_ 256
#define V_ 16000

typedef __attribute__((ext_vector_type(4))) float f32x4_t;
typedef __attribute__((ext_vector_type(2))) float f32x2_t;
typedef __attribute__((ext_vector_type(8))) short bf16x8_t;
typedef __attribute__((ext_vector_type(2))) unsigned u32x2_t;
typedef __attribute__((ext_vector_type(4))) unsigned u32x4_t;

#define W2_SCALE 64.0f
#define W2_INV   0.015625f

// packed f32->bf16 RNE, 1 inst per 2 elems
__device__ __forceinline__ bf16x8_t pack8(f32x4_t a, f32x4_t b) {
    union { unsigned u[4]; bf16x8_t v; } o;
    asm("v_cvt_pk_bf16_f32 %0, %1, %2" : "=v"(o.u[0]) : "v"(a[0]), "v"(a[1]));
    asm("v_cvt_pk_bf16_f32 %0, %1, %2" : "=v"(o.u[1]) : "v"(a[2]), "v"(a[3]));
    asm("v_cvt_pk_bf16_f32 %0, %1, %2" : "=v"(o.u[2]) : "v"(b[0]), "v"(b[1]));
    asm("v_cvt_pk_bf16_f32 %0, %1, %2" : "=v"(o.u[3]) : "v"(b[2]), "v"(b[3]));
    return o.v;
}

__device__ __forceinline__ void cvt8(short* dst, const float* src) {
    f32x4_t a = *(const f32x4_t*)src;
    f32x4_t b = *(const f32x4_t*)(src + 4);
    *(bf16x8_t*)dst = pack8(a, b);
}

// 8 f32 -> 8 fp8 e4m3 packed in 2 dwords (4 cvt_pk inst)
__device__ __forceinline__ u32x2_t f32x8_to_fp8x8(f32x4_t a, f32x4_t b, float s) {
    unsigned d0 = 0, d1 = 0;
    d0 = __builtin_amdgcn_cvt_pk_fp8_f32(a[0] * s, a[1] * s, d0, false);
    d0 = __builtin_amdgcn_cvt_pk_fp8_f32(a[2] * s, a[3] * s, d0, true);
    d1 = __builtin_amdgcn_cvt_pk_fp8_f32(b[0] * s, b[1] * s, d1, false);
    d1 = __builtin_amdgcn_cvt_pk_fp8_f32(b[2] * s, b[3] * s, d1, true);
    u32x2_t r; r[0] = d0; r[1] = d1;
    return r;
}

// tanh = 1 - 2/(exp(2x)+1): 5 flat VALU, saturates correctly at +-inf
__device__ __forceinline__ float tanh5(float x) {
    float e = __expf(2.f * x);
    return 1.f - 2.f * __builtin_amdgcn_rcpf(e + 1.f);
}

// LDS chunk swizzle: row has 64 chunks; interleave chunk bits + XOR row.
__device__ __forceinline__ int physc(int c, int r) {
    return ((((c & 7) << 3) | (c >> 3)) ^ (r & 7));
}

// ---------------------------------------------------------------------------
// setup_kernel: one launch fusing three independent setup steps (saves 2
// launch gaps on the serialized stream):
//  blocks   0..31  : pack_w2 - W2 (scaled x64) -> PAIRED fp8 fragments
//  blocks  32..159 : prep    - emb gather + h into x_cat (bf16), 2 batches/blk
//  blocks 160..287 : bias1   - h @ W1^T + attn_b, 2 batches/blk (has barrier)
// ---------------------------------------------------------------------------
__global__ __launch_bounds__(512)
void setup_kernel(const int* __restrict__ tgt,
                  const float* __restrict__ emb,
                  const float* __restrict__ hidden,
                  const float* __restrict__ attn_W,
                  const float* __restrict__ attn_b,
                  short* __restrict__ x_cat,
                  unsigned* __restrict__ Bp,
                  float* __restrict__ bias1)
{
    __shared__ float h_s[2][512];
    const int bid = blockIdx.x;
    const int t   = threadIdx.x;             // 0..511

    if (bid < 32) {
        // ---- pack_w2: 16B unit u = (kk*8+wn)*2+p)*64+lane layout (r15)
        const int u    = bid * 512 + t;      // 0..16383
        const int lane = u & 63;
        const int p    = (u >> 6) & 1;
        const int wn   = (u >> 7) & 7;
        const int kk   = u >> 10;            // 0..15
        const int col0 = wn * 64 + (2 * p) * 16 + (lane & 15);
        const int k    = kk * 32 + (lane >> 4) * 8;
        const float* s0 = attn_W + (size_t)col0 * (2 * H_) + H_ + k;
        const float* s1 = s0 + (size_t)16 * (2 * H_);     // col0 + 16
        f32x4_t a0 = *(const f32x4_t*)s0, b0 = *(const f32x4_t*)(s0 + 4);
        f32x4_t a1 = *(const f32x4_t*)s1, b1 = *(const f32x4_t*)(s1 + 4);
        u32x2_t lo = f32x8_to_fp8x8(a0, b0, W2_SCALE);
        u32x2_t hi = f32x8_to_fp8x8(a1, b1, W2_SCALE);
        u32x4_t st; st[0] = lo[0]; st[1] = lo[1]; st[2] = hi[0]; st[3] = hi[1];
        *(u32x4_t*)(Bp + (size_t)u * 4) = st;
        return;
    }

    if (bid < 160) {
        // ---- prep: 2 batches per block
        const int b  = (bid - 32) * 2 + (t >> 8);
        const int tt = t & 255;
        const int tok = tgt[b];
        union { float f; unsigned u; } v0, v1, v2;
        v0.f = emb[(size_t)tok * E_ + tt];
        v1.f = hidden[(size_t)b * H_ + tt];
        v2.f = hidden[(size_t)b * H_ + 256 + tt];
        unsigned r0 = v0.u + 0x7fffu + ((v0.u >> 16) & 1u);
        unsigned r1 = v1.u + 0x7fffu + ((v1.u >> 16) & 1u);
        unsigned r2 = v2.u + 0x7fffu + ((v2.u >> 16) & 1u);
        x_cat[(size_t)b * 1280 + tt]             = (short)(r0 >> 16);
        x_cat[(size_t)b * 1280 + 768 + tt]       = (short)(r1 >> 16);
        x_cat[(size_t)b * 1280 + 768 + 256 + tt] = (short)(r2 >> 16);
        return;
    }

    // ---- bias1: 2 batches per block (all 512 threads take this path)
    const int b0 = (bid - 160) * 2;
    h_s[0][t] = hidden[(size_t)b0 * H_ + t];
    h_s[1][t] = hidden[(size_t)(b0 + 1) * H_ + t];
    __syncthreads();
    const float* wrow = attn_W + (size_t)t * (2 * H_);     // W1 part: cols 0..511
    float a0 = 0.f, a1 = 0.f;
#pragma unroll 4
    for (int k = 0; k < 512; k += 4) {
        f32x4_t wv = *(const f32x4_t*)(wrow + k);
        a0 = fmaf(wv[0], h_s[0][k],     a0);
        a0 = fmaf(wv[1], h_s[0][k + 1], a0);
        a0 = fmaf(wv[2], h_s[0][k + 2], a0);
        a0 = fmaf(wv[3], h_s[0][k + 3], a0);
        a1 = fmaf(wv[0], h_s[1][k],     a1);
        a1 = fmaf(wv[1], h_s[1][k + 1], a1);
        a1 = fmaf(wv[2], h_s[1][k + 2], a1);
        a1 = fmaf(wv[3], h_s[1][k + 3], a1);
    }
    const float bb = attn_b[t];
    bias1[(size_t)b0 * H_ + t]       = a0 + bb;
    bias1[(size_t)(b0 + 1) * H_ + t] = a1 + bb;
}

// ---------------------------------------------------------------------------
// fused_attn: 4096 blocks (16 per batch, ONE 32-row tile each), 512 threads.
// Native fp8 MFMA; PAIRED B fragments (one dwordx4 per lane = 2 fragments).
// r15-proven: VGPR 40, no spill, 64% occupancy, 201 us total. (r16's 64-row
// 1024-thr variant regressed: 1024-thr blocks never get 2 blocks/CU on this
// stack, and its remapped ctx/staging reintroduced 4-way bank conflicts.)
// ---------------------------------------------------------------------------
__global__ void fused_attn(const float* __restrict__ enc,
                           const unsigned* __restrict__ Bp,
                           const float* __restrict__ bias1,
                           const float* __restrict__ vvec,
                           float* __restrict__ e_ws,
                           float* __restrict__ lpart,
                           float* __restrict__ ctxpart)
{
    __shared__ unsigned char buf8[32 * 512]; // 16 KB fp8 tile, swizzled 8B chunks
    __shared__ float bias_s[512];
    __shared__ float v_s[512];
    __shared__ float red[32][9];
    __shared__ float e_loc[32];

    const int t    = threadIdx.x;
    const int lane = t & 63;
    const int w    = t >> 6;                 // 0..7, col group (64 cols)
    const int b    = blockIdx.x >> 4;        // batch
    const int q    = blockIdx.x & 15;        // 32-row slice

    bias_s[t] = bias1[(size_t)b * H_ + t];
    v_s[t]    = vvec[t];

    // ---- stage 32x512 f32 -> fp8 swizzled LDS (128B coalesced/thread)
    const int srow = t >> 4;                 // 0..31
    const int sc   = t & 15;
    const float* gp = enc + ((size_t)b * S_ + q * 32 + srow) * H_ + sc * 32;
#pragma unroll
    for (int i = 0; i < 4; ++i) {
        f32x4_t a = *(const f32x4_t*)(gp + i * 8);
        f32x4_t c = *(const f32x4_t*)(gp + i * 8 + 4);
        *(u32x2_t*)&buf8[srow * 512 + physc(sc * 4 + i, srow) * 8] =
            f32x8_to_fp8x8(a, c, 1.0f);
    }
    __syncthreads();

    // ---- GEMM: 32 rows x 64 cols (this wave) x K=512, fp8 x fp8
    const int l15 = lane & 15;
    const int hi  = lane >> 4;               // 0..3
    const int Y   = l15 & 7;
    const unsigned char* abase = buf8 + l15 * 512 + hi * 64; // + mf*8192, par*256 imm
    const unsigned* bbase = Bp + (size_t)w * 512 + lane * 4; // + kk2*8192 + par*4096 [+256]

    f32x4_t acc[2][4];
#pragma unroll
    for (int mf = 0; mf < 2; ++mf)
#pragma unroll
        for (int nf = 0; nf < 4; ++nf)
            acc[mf][nf] = (f32x4_t){0.f, 0.f, 0.f, 0.f};

#pragma unroll
    for (int kk2 = 0; kk2 < 8; ++kk2) {
        const unsigned char* ap = abase + ((kk2 ^ Y) << 3);
        const unsigned* bp = bbase + (size_t)kk2 * 8192;
#pragma unroll
        for (int par = 0; par < 2; ++par) {
            const unsigned char* app = ap + par * 256;
            const unsigned* bpp = bp + par * 4096;
            long a0 = *(const long*)(app);
            long a1 = *(const long*)(app + 8192);
            union { u32x4_t v; long l[2]; } q0, q1;
            q0.v = *(const u32x4_t*)(bpp);        // frags nf0, nf1
            q1.v = *(const u32x4_t*)(bpp + 256);  // frags nf2, nf3
            __builtin_amdgcn_s_setprio(1);
            acc[0][0] = __builtin_amdgcn_mfma_f32_16x16x32_fp8_fp8(a0, q0.l[0], acc[0][0], 0, 0, 0);
            acc[1][0] = __builtin_amdgcn_mfma_f32_16x16x32_fp8_fp8(a1, q0.l[0], acc[1][0], 0, 0, 0);
            acc[0][1] = __builtin_amdgcn_mfma_f32_16x16x32_fp8_fp8(a0, q0.l[1], acc[0][1], 0, 0, 0);
            acc[1][1] = __builtin_amdgcn_mfma_f32_16x16x32_fp8_fp8(a1, q0.l[1], acc[1][1], 0, 0, 0);
            acc[0][2] = __builtin_amdgcn_mfma_f32_16x16x32_fp8_fp8(a0, q1.l[0], acc[0][2], 0, 0, 0);
            acc[1][2] = __builtin_amdgcn_mfma_f32_16x16x32_fp8_fp8(a1, q1.l[0], acc[1][2], 0, 0, 0);
            acc[0][3] = __builtin_amdgcn_mfma_f32_16x16x32_fp8_fp8(a0, q1.l[1], acc[0][3], 0, 0, 0);
            acc[1][3] = __builtin_amdgcn_mfma_f32_16x16x32_fp8_fp8(a1, q1.l[1], acc[1][3], 0, 0, 0);
            __builtin_amdgcn_s_setprio(0);
        }
    }

    // ---- epilogue: per-wave partial score over its 64 cols
    float part[8];
#pragma unroll
    for (int i = 0; i < 8; ++i) part[i] = 0.f;
#pragma unroll
    for (int nf = 0; nf < 4; ++nf) {
        const int col = w * 64 + nf * 16 + l15;
        const float bbv = bias_s[col];
        const float vl  = v_s[col];
#pragma unroll
        for (int mf = 0; mf < 2; ++mf)
#pragma unroll
            for (int r = 0; r < 4; ++r)
                part[mf * 4 + r] += vl * tanh5(fmaf(acc[mf][nf][r], W2_INV, bbv));
    }
#pragma unroll
    for (int i = 0; i < 8; ++i) {
        float p = part[i];
        p += __shfl_xor(p, 1);
        p += __shfl_xor(p, 2);
        p += __shfl_xor(p, 4);
        p += __shfl_xor(p, 8);
        part[i] = p;
    }
    if (l15 == 0) {
#pragma unroll
        for (int mf = 0; mf < 2; ++mf)
#pragma unroll
            for (int r = 0; r < 4; ++r)
                red[mf * 16 + (hi << 2) + r][w] = part[mf * 4 + r];
    }
    __syncthreads();                          // red visible

    if (t < 32) {
        float s = red[t][0] + red[t][1] + red[t][2] + red[t][3]
                + red[t][4] + red[t][5] + red[t][6] + red[t][7];
        e_loc[t] = __expf(s);
    }
    __syncthreads();                          // e_loc visible

    // ---- context partial from fp8 tile: rows r = i*8+cg, chunk cc
    const int cg = lane >> 3;                 // 0..7
    const int cc = (lane & 7) * 8 + w;        // 0..63
    float acc8[8];
#pragma unroll
    for (int j = 0; j < 8; ++j) acc8[j] = 0.f;
#pragma unroll
    for (int i = 0; i < 4; ++i) {
        const int r   = i * 8 + cg;
        const float e = e_loc[r];
        u32x2_t ch = *(const u32x2_t*)&buf8[r * 512 + physc(cc, r) * 8];
        f32x2_t f0 = __builtin_amdgcn_cvt_pk_f32_fp8(ch[0], false);
        f32x2_t f1 = __builtin_amdgcn_cvt_pk_f32_fp8(ch[0], true);
        f32x2_t f2 = __builtin_amdgcn_cvt_pk_f32_fp8(ch[1], false);
        f32x2_t f3 = __builtin_amdgcn_cvt_pk_f32_fp8(ch[1], true);
        acc8[0] = fmaf(e, f0[0], acc8[0]);
        acc8[1] = fmaf(e, f0[1], acc8[1]);
        acc8[2] = fmaf(e, f1[0], acc8[2]);
        acc8[3] = fmaf(e, f1[1], acc8[3]);
        acc8[4] = fmaf(e, f2[0], acc8[4]);
        acc8[5] = fmaf(e, f2[1], acc8[5]);
        acc8[6] = fmaf(e, f3[0], acc8[6]);
        acc8[7] = fmaf(e, f3[1], acc8[7]);
    }
    // reduce over cg (lanes differing in bits 3..5)
#pragma unroll
    for (int m = 8; m < 64; m <<= 1)
#pragma unroll
        for (int j = 0; j < 8; ++j)
            acc8[j] += __shfl_xor(acc8[j], m);
#pragma unroll
    for (int j = 0; j < 8; ++j)               // static index (rule #20)
        if (cg == j)
            ctxpart[(size_t)blockIdx.x * H_ + cc * 8 + j] = acc8[j];

    // ---- l partial + e out (32 rows)
    if (t < 32) {
        float sv = e_loc[t];
        sv += __shfl_xor(sv, 1);
        sv += __shfl_xor(sv, 2);
        sv += __shfl_xor(sv, 4);
        sv += __shfl_xor(sv, 8);
        sv += __shfl_xor(sv, 16);
        if (lane == 0) lpart[blockIdx.x] = sv;
        e_ws[(size_t)b * S_ + q * 32 + t] = e_loc[t];
    }
}

// ---------------------------------------------------------------------------
// combine: normalize softmax pieces from the 16 row-slice blocks per batch.
// ---------------------------------------------------------------------------
__global__ void combine_kernel(const float* __restrict__ e_ws,
                               const float* __restrict__ lpart,
                               const float* __restrict__ ctxpart,
                               float* __restrict__ out_attn,
                               short* __restrict__ x_cat)
{
    const int b = blockIdx.x, t = threadIdx.x;          // 512 threads
    float l = 0.f;
#pragma unroll
    for (int j = 0; j < 16; ++j) l += lpart[16 * b + j];
    const float li = 1.f / l;
    out_attn[(size_t)b * S_ + t] = e_ws[(size_t)b * S_ + t] * li;
    float ctx = 0.f;
#pragma unroll
    for (int j = 0; j < 16; ++j)
        ctx += ctxpart[(size_t)(16 * b + j) * H_ + t];
    union { float f; unsigned u; } v; v.f = ctx * li;
    unsigned r = v.u + 0x7fffu + ((v.u >> 16) & 1u);
    x_cat[(size_t)b * 1280 + 256 + t] = (short)(r >> 16);
}

// ---------------------------------------------------------------------------
// gemm_std: BM=128, BN=128, BK=32, 4 waves (256 thr). A is pre-converted bf16.
// KIND 0 (gates): split-K via blockIdx.z (2 halves of 640), NO bias (lstm
//                 adds b_ih+b_hh when summing the two partials).
// KIND 1 (pred):  K=512, N=16000, B = fc_W rows, bias = fc_b.
// ---------------------------------------------------------------------------
template<int KIND>
__global__ __launch_bounds__(256, 2)
void gemm_std(const short* __restrict__ Abf,
              const float* __restrict__ B0,
              const float* __restrict__ B1,
              const float* __restrict__ bias0,
              float* __restrict__ out)
{
    constexpr int K = (KIND == 0) ? 1280 : 512;
    constexpr int N = (KIND == 0) ? 2048 : 16000;
    constexpr int KITER = (KIND == 0) ? 20 : 16;         // ks steps per block

    __shared__ short As[128 * 40];
    __shared__ short Bs[128 * 40];

    const int t    = threadIdx.x;
    const int lane = t & 63;
    const int w    = t >> 6;
    const int wm   = w >> 1;
    const int wn   = w & 1;
    const int row0 = blockIdx.x * 128;
    const int col0 = blockIdx.y * 128;
    const int z    = (KIND == 0) ? blockIdx.z : 0;
    const int ks0  = z * KITER;
    float* outp    = (KIND == 0) ? out + (size_t)z * 256 * 2048 : out;

    f32x4_t acc[4][4];
#pragma unroll
    for (int i = 0; i < 4; ++i)
#pragma unroll
        for (int j = 0; j < 4; ++j)
            acc[i][j] = (f32x4_t){0.f, 0.f, 0.f, 0.f};

    const int arow = t >> 1, ah = (t & 1) * 16;
    const int bcol = t >> 1, bh = (t & 1) * 16;

    for (int ksi = 0; ksi < KITER; ++ksi) {
        const int k0 = (ks0 + ksi) * 32;
        __syncthreads();
        const short* asrc = Abf + (size_t)(row0 + arow) * K + k0 + ah;
        *(bf16x8_t*)&As[arow * 40 + ah]     = *(const bf16x8_t*)asrc;
        *(bf16x8_t*)&As[arow * 40 + ah + 8] = *(const bf16x8_t*)(asrc + 8);
        const float* bsrc;
        if constexpr (KIND == 0) {
            const int cg = col0 + bcol;
            bsrc = (k0 < 768) ? (B0 + (size_t)cg * 768 + k0 + bh)
                              : (B1 + (size_t)cg * 512 + (k0 - 768) + bh);
        } else {
            bsrc = B0 + (size_t)(col0 + bcol) * 512 + k0 + bh;
        }
        cvt8(&Bs[bcol * 40 + bh],     bsrc);
        cvt8(&Bs[bcol * 40 + bh + 8], bsrc + 8);
        __syncthreads();

        bf16x8_t af[4], bfr[4];
        const int ka = (lane >> 4) * 8;
#pragma unroll
        for (int mf = 0; mf < 4; ++mf)
            af[mf] = *(const bf16x8_t*)&As[(wm * 64 + mf * 16 + (lane & 15)) * 40 + ka];
#pragma unroll
        for (int nf = 0; nf < 4; ++nf)
            bfr[nf] = *(const bf16x8_t*)&Bs[(wn * 64 + nf * 16 + (lane & 15)) * 40 + ka];
#pragma unroll
        for (int mf = 0; mf < 4; ++mf)
#pragma unroll
            for (int nf = 0; nf < 4; ++nf)
                acc[mf][nf] = __builtin_amdgcn_mfma_f32_16x16x32_bf16(
                    af[mf], bfr[nf], acc[mf][nf], 0, 0, 0);
    }

#pragma unroll
    for (int mf = 0; mf < 4; ++mf)
#pragma unroll
        for (int nf = 0; nf < 4; ++nf) {
            const int col  = col0 + wn * 64 + nf * 16 + (lane & 15);
            const int rowb = row0 + wm * 64 + mf * 16 + ((lane >> 4) << 2);
#pragma unroll
            for (int r = 0; r < 4; ++r) {
                float v = acc[mf][nf][r];
                if constexpr (KIND == 1) v += bias0[col];
                outp[(size_t)(rowb + r) * N + col] = v;
            }
        }
}

// ---------------------------------------------------------------------------
// lstm: sums the two split-K gate partials + both biases, then pointwise.
// ---------------------------------------------------------------------------
__global__ void lstm_kernel(const float* __restrict__ gates0,
                            const float* __restrict__ gates1,
                            const float* __restrict__ b_ih,
                            const float* __restrict__ b_hh,
                            const float* __restrict__ cell,
                            float* __restrict__ out_h,
                            float* __restrict__ out_c,
                            short* __restrict__ h_bf)
{
    const int b = blockIdx.x, t = threadIdx.x;          // 512 threads
    const float* g0 = gates0 + (size_t)b * 2048;
    const float* g1 = gates1 + (size_t)b * 2048;
    const float gi = g0[t]        + g1[t]        + b_ih[t]        + b_hh[t];
    const float gf = g0[512 + t]  + g1[512 + t]  + b_ih[512 + t]  + b_hh[512 + t];
    const float gg = g0[1024 + t] + g1[1024 + t] + b_ih[1024 + t] + b_hh[1024 + t];
    const float go = g0[1536 + t] + g1[1536 + t] + b_ih[1536 + t] + b_hh[1536 + t];
    const float c  = cell[(size_t)b * H_ + t];
    const float si = 1.f / (1.f + __expf(-gi));
    const float sf = 1.f / (1.f + __expf(-gf));
    const float so = 1.f / (1.f + __expf(-go));
    const float cn = sf * c + si * tanhf(gg);
    const float hn = so * tanhf(cn);
    out_h[(size_t)b * H_ + t] = hn;
    out_c[(size_t)b * H_ + t] = cn;
    union { float f; unsigned u; } v; v.f = hn;
    unsigned r = v.u + 0x7fffu + ((v.u >> 16) & 1u);
    h_bf[(size_t)b * H_ + t]  = (short)(r >> 16);
}

// ---------------------------------------------------------------------------
extern "C" void kernel_launch(void* const* d_in, const int* in_sizes, int n_in,
                              void* d_out, int out_size, void* d_ws, size_t ws_size,
                              hipStream_t stream)
{
    (void)in_sizes; (void)n_in; (void)out_size; (void)ws_size;

    const int*   tgt    = (const int*)d_in[0];
    const float* hidden = (const float*)d_in[1];
    const float* cell   = (const float*)d_in[2];
    const float* enc    = (const float*)d_in[3];
    const float* emb    = (const float*)d_in[4];
    const float* attn_W = (const float*)d_in[5];
    const float* attn_b = (const float*)d_in[6];
    const float* vv     = (const float*)d_in[7];
    const float* W_ih   = (const float*)d_in[8];
    const float* W_hh   = (const float*)d_in[9];
    const float* b_ih   = (const float*)d_in[10];
    const float* b_hh   = (const float*)d_in[11];
    const float* fc_W   = (const float*)d_in[12];
    const float* fc_b   = (const float*)d_in[13];

    float* out_pred = (float*)d_out;                       // [256][16000]
    float* out_h    = out_pred + (size_t)B_ * V_;          // [256][512]
    float* out_c    = out_h + (size_t)B_ * H_;             // [256][512]
    float* out_attn = out_c + (size_t)B_ * H_;             // [256][512]

    char*  ws      = (char*)d_ws;
    float* bias1   = (float*)ws;                           // 131072 f32
    float* gates01 = bias1 + (size_t)B_ * H_;              // 2 x 524288 f32
    float* e_ws    = gates01 + (size_t)2 * B_ * 2048;      // 131072 f32
    float* lpart   = e_ws + (size_t)B_ * S_;               // 4096 f32
    float* ctxpart = lpart + 4096;                         // 4096*512 f32
    short* x_cat   = (short*)(ctxpart + (size_t)4096 * H_);// 327680 bf16
    short* h_bf    = x_cat + (size_t)B_ * 1280;            // 131072 bf16
    unsigned* b2p  = (unsigned*)(h_bf + (size_t)B_ * H_);  // 65536 dwords (fp8)

    // 1. fused setup: pack_w2 (32 blks) + prep (128 blks) + bias1 (128 blks)
    setup_kernel<<<288, 512, 0, stream>>>(tgt, emb, hidden, attn_W, attn_b,
                                          x_cat, b2p, bias1);
    // 2. fused attention partials: 16 blocks per batch (32 rows each)
    fused_attn<<<16 * B_, 512, 0, stream>>>(enc, b2p, bias1, vv, e_ws, lpart, ctxpart);
    // 3. combine partials -> attn out + ctx slice of x_cat
    combine_kernel<<<B_, 512, 0, stream>>>(e_ws, lpart, ctxpart, out_attn, x_cat);
    // 4. gates partials = x_cat @ [W_ih|W_hh]^T  (split-K, 2 halves, no bias)
    gemm_std<0><<<dim3(2, 16, 2), 256, 0, stream>>>(x_cat, W_ih, W_hh, nullptr, gates01);
    // 5. LSTM pointwise (sums partials + biases)
    lstm_kernel<<<B_, 512, 0, stream>>>(gates01, gates01 + (size_t)B_ * 2048,
                                        b_ih, b_hh, cell, out_h, out_c, h_bf);
    // 6. prediction = h_new @ fc_W^T + fc_b
    gemm_std<1><<<dim3(2, 125), 256, 0, stream>>>(h_bf, fc_W, nullptr, fc_b, out_pred);
}